// Round 1
// baseline (55.316 us; speedup 1.0000x reference)
//
#include <hip/hip_runtime.h>

// Closed-form: the circuit is RX layer on |0..0> (product state) + CNOT ring
// (Clifford) + Z_w readout. Conjugating Z_w through the ring gives Pauli-Z
// strings over wire sets S(0)={1..11}, S(k)={0..k} for k>=1, and the product
// state gives <Z_S> = prod_{w in S} cos(x_w + theta_w).

constexpr int N_WIRES = 12;
constexpr int BATCH   = 2048;

__global__ __launch_bounds__(256) void qlstm_zexp_kernel(
    const float* __restrict__ x,      // (BATCH, N_WIRES)
    const float* __restrict__ theta,  // (N_WIRES,)
    float* __restrict__ out)          // (BATCH, N_WIRES)
{
    const int b = blockIdx.x * blockDim.x + threadIdx.x;
    if (b >= BATCH) return;

    // theta is wave-uniform; loads broadcast out of L1.
    float th[N_WIRES];
#pragma unroll
    for (int w = 0; w < N_WIRES; ++w) th[w] = theta[w];

    // Row = 12 floats = 48 B, 16B-aligned -> 3x float4 loads.
    const float4* xv = reinterpret_cast<const float4*>(x + (size_t)b * N_WIRES);
    const float4 a0 = xv[0], a1 = xv[1], a2 = xv[2];
    const float xs[N_WIRES] = {a0.x, a0.y, a0.z, a0.w,
                               a1.x, a1.y, a1.z, a1.w,
                               a2.x, a2.y, a2.z, a2.w};

    float c[N_WIRES];
#pragma unroll
    for (int w = 0; w < N_WIRES; ++w) c[w] = cosf(xs[w] + th[w]);

    float o[N_WIRES];
    // out[k] = prefix product c0..ck for k >= 1
    float p = c[0];
#pragma unroll
    for (int k = 1; k < N_WIRES; ++k) { p *= c[k]; o[k] = p; }
    // out[0] = product c1..c11 (no division: c0 may be ~0)
    float q = c[1];
#pragma unroll
    for (int w = 2; w < N_WIRES; ++w) q *= c[w];
    o[0] = q;

    float4* ov = reinterpret_cast<float4*>(out + (size_t)b * N_WIRES);
    ov[0] = make_float4(o[0], o[1], o[2],  o[3]);
    ov[1] = make_float4(o[4], o[5], o[6],  o[7]);
    ov[2] = make_float4(o[8], o[9], o[10], o[11]);
}

extern "C" void kernel_launch(void* const* d_in, const int* in_sizes, int n_in,
                              void* d_out, int out_size, void* d_ws, size_t ws_size,
                              hipStream_t stream) {
    const float* x     = (const float*)d_in[0];   // (2048, 12) fp32
    const float* theta = (const float*)d_in[1];   // (12,) fp32
    float* out = (float*)d_out;                   // (2048, 12) fp32

    const int block = 256;
    const int grid  = (BATCH + block - 1) / block;  // 8 blocks
    qlstm_zexp_kernel<<<grid, block, 0, stream>>>(x, theta, out);
}

// Round 2
// 54.056 us; speedup vs baseline: 1.0233x; 1.0233x over previous
//
#include <hip/hip_runtime.h>

// Closed-form: RX layer on |0..0> (product state) + CNOT ring (Clifford) +
// Z_w readout. Conjugating Z_w back through the ring yields Pauli-Z strings
// over wire sets S(0)={1..11}, S(k)={0..k} (k>=1); product state gives
// <Z_S> = prod_{w in S} cos(x_w + theta_w).
//
// out[b][0] = prod_{w=1..11} cos(x[b][w]+theta[w])
// out[b][k] = prod_{w=0..k}  cos(x[b][w]+theta[w])   (prefix product)

constexpr int N_WIRES = 12;
constexpr int BATCH   = 2048;

__global__ __launch_bounds__(64) void qlstm_zexp_kernel(
    const float* __restrict__ x,      // (BATCH, N_WIRES)
    const float* __restrict__ theta,  // (N_WIRES,)
    float* __restrict__ out)          // (BATCH, N_WIRES)
{
    const int b = blockIdx.x * blockDim.x + threadIdx.x;
    if (b >= BATCH) return;

    // theta is wave-uniform with constant indices -> scalar (s_load) broadcasts.
    float th[N_WIRES];
#pragma unroll
    for (int w = 0; w < N_WIRES; ++w) th[w] = theta[w];

    // Row = 12 floats = 48 B, 16B-aligned -> 3x float4 loads.
    const float4* xv = reinterpret_cast<const float4*>(x + (size_t)b * N_WIRES);
    const float4 a0 = xv[0], a1 = xv[1], a2 = xv[2];
    const float xs[N_WIRES] = {a0.x, a0.y, a0.z, a0.w,
                               a1.x, a1.y, a1.z, a1.w,
                               a2.x, a2.y, a2.z, a2.w};

    // |x+theta| <~ 9: __cosf (v_fract + v_cos_f32) is ~1e-5 accurate here,
    // vs 2e-2 pass threshold.
    float c[N_WIRES];
#pragma unroll
    for (int w = 0; w < N_WIRES; ++w) c[w] = __cosf(xs[w] + th[w]);

    float o[N_WIRES];
    float p = c[0];
#pragma unroll
    for (int k = 1; k < N_WIRES; ++k) { p *= c[k]; o[k] = p; }
    float q = c[1];
#pragma unroll
    for (int w = 2; w < N_WIRES; ++w) q *= c[w];
    o[0] = q;

    float4* ov = reinterpret_cast<float4*>(out + (size_t)b * N_WIRES);
    ov[0] = make_float4(o[0], o[1], o[2],  o[3]);
    ov[1] = make_float4(o[4], o[5], o[6],  o[7]);
    ov[2] = make_float4(o[8], o[9], o[10], o[11]);
}

extern "C" void kernel_launch(void* const* d_in, const int* in_sizes, int n_in,
                              void* d_out, int out_size, void* d_ws, size_t ws_size,
                              hipStream_t stream) {
    const float* x     = (const float*)d_in[0];   // (2048, 12) fp32
    const float* theta = (const float*)d_in[1];   // (12,) fp32
    float* out = (float*)d_out;                   // (2048, 12) fp32

    // 32 blocks x 64 threads: one wave per block, spread over 32 CUs so the
    // single dependent load->cos->store chain overlaps across CUs.
    const int block = 64;
    const int grid  = BATCH / block;  // 32
    qlstm_zexp_kernel<<<grid, block, 0, stream>>>(x, theta, out);
}